// Round 8
// baseline (453.397 us; speedup 1.0000x reference)
//
#include <hip/hip_runtime.h>
#include <math.h>

// B=16, C_IN=256, C_OUT=256, H=W=64, K=3, NK=2
// weights: [2][256][256][3][3]; bank stride 589824 floats; per-o stride 2304.
//
// Pipeline:
//  1. wprep (fused scale+prep): per (b, o-octet) block computes demod scale and
//     writes combined+modulated+demod bf16 weights into wq, LDS-image layout
//     per (b,ot2,c16): [p=20][ol=128][e=8], p = io*10 + j (j=9 zero dummy tap).
//     Chunk = 20480 ushorts; p-stride 1024 ushorts, ol-stride 8 ushorts.
//  2. xprep: x -> bf16 xq [b][c16][rowp 66][colp 66][i 16], halo zeros baked,
//     PRE-SWIZZLED (XOR bank swizzle baked in) for conflict-light ds_read.
//  3. conv_mfma: implicit GEMM via mfma_f32_16x16x32_bf16. Block = 512 thr
//     (8 waves) = 128 o x 8 rows x 64 px; grid 256. K-loop software-pipelined
//     at ds_read level: reads for phase s+1 issued BEFORE MFMAs of phase s
//     (P/Q register double-buffer, sched_barrier pins, compiler emits counted
//     lgkmcnt) so the LDS pipe and MFMA pipe overlap instead of serializing.
//     GLL staging for c+1 issued phases 0-3, drained (covered) at c-boundary.
//  4. norm_kernel: channel RMSNorm * gamma * 16 + SiLU in place.

typedef __attribute__((ext_vector_type(8))) short short8;
typedef __attribute__((ext_vector_type(4))) float f32x4;

#define GLL16(src, dst)                                                       \
  __builtin_amdgcn_global_load_lds(                                           \
      (const __attribute__((address_space(1))) unsigned int*)(src),           \
      (__attribute__((address_space(3))) unsigned int*)(dst), 16, 0, 0)

static __device__ __forceinline__ unsigned short f2bf(float v) {
  union { float f; unsigned u; } u;
  u.f = v;
  unsigned r = u.u + 0x7FFF + ((u.u >> 16) & 1);  // RNE
  return (unsigned short)(r >> 16);
}

// ---------------------------------------------------------------------------
// Kernel 1: fused weight prep. Grid 512 = b(16) x oq(32 o-octets), 256 thr.
// Thread t: o_l = t>>5 (octet member), its = t&31 -> i-slice its*8..+8.
// Pass A: combined+modulated weights -> regs + sumsq reduce -> scale.
// Pass B: scale+convert+write LDS-image chunks. Also zero dummy taps.
// ---------------------------------------------------------------------------
__global__ __launch_bounds__(256) void wprep(
    const float* __restrict__ mod, const float* __restrict__ kmod,
    const float* __restrict__ weights, unsigned short* __restrict__ wq) {
  int blk = blockIdx.x;  // b*32 + oq
  int b = blk >> 5, oq = blk & 31;
  int t = threadIdx.x;
  int o_l = t >> 5, its = t & 31;
  int o = oq * 8 + o_l;

  float k0 = kmod[b * 2 + 0], k1 = kmod[b * 2 + 1];
  float mx = fmaxf(k0, k1);
  float e0 = expf(k0 - mx), e1 = expf(k1 - mx);
  float ai = 1.0f / (e0 + e1);
  float a0 = e0 * ai, a1 = e1 * ai;

  float wv[9][8];  // [j][e]
  float s = 0.0f;
  const float* w0 = &weights[((size_t)o * 256 + its * 8) * 9];
  const float* w1 = w0 + 589824;
#pragma unroll
  for (int e = 0; e < 8; ++e) {
    float f = mod[b * 256 + its * 8 + e] + 1.0f;
#pragma unroll
    for (int j = 0; j < 9; ++j) {
      float v = (a0 * w0[e * 9 + j] + a1 * w1[e * 9 + j]) * f;
      wv[j][e] = v;
      s = fmaf(v, v, s);
    }
  }

  __shared__ float red[8][32];
  __shared__ float scl[8];
  red[o_l][its] = s;
  __syncthreads();
  if (t < 8) {
    float tot = 0.0f;
#pragma unroll
    for (int k = 0; k < 32; ++k) tot += red[t][k];
    scl[t] = rsqrtf(fmaxf(tot, 1e-8f));
  }
  __syncthreads();
  float sc = scl[o_l];

  int c = its >> 1, io = its & 1;
  int ot = o >> 7, ol = o & 127;
  // chunk layout [p20][ol128][e8] in USHORT units: p-stride 1024, ol-stride 8
  size_t base = ((size_t)(b * 32 + ot * 16 + c)) * 20480 + ol * 8;
#pragma unroll
  for (int j = 0; j < 9; ++j) {
    short8 pk;
#pragma unroll
    for (int e = 0; e < 8; ++e) pk[e] = (short)f2bf(wv[j][e] * sc);
    *(short8*)(wq + base + (io * 10 + j) * 1024) = pk;
  }
  // dummy-tap zeros: this block covers its 8 o x 16 c x 2 io slots
  {
    int c2 = t >> 4, io2 = (t >> 3) & 1, olq = t & 7;
    int o2 = oq * 8 + olq;
    int ot2 = o2 >> 7, olz = o2 & 127;
    short8 z = {0, 0, 0, 0, 0, 0, 0, 0};
    *(short8*)(wq + ((size_t)(b * 32 + ot2 * 16 + c2)) * 20480 +
               (io2 * 10 + 9) * 1024 + olz * 8) = z;
  }
}

// ---------------------------------------------------------------------------
// Kernel 2: x prep -> bf16 xq, pre-swizzled.
// ---------------------------------------------------------------------------
__global__ __launch_bounds__(256) void xprep(
    const float* __restrict__ x, unsigned short* __restrict__ xq) {
  int blk = blockIdx.x;  // (b*16 + c)*66 + rowp
  int rowp = blk % 66;
  int bc = blk / 66;
  int b = bc >> 4, c = bc & 15;
  int t = threadIdx.x;
  size_t obase = (size_t)blk * 1056;

  if (rowp == 0 || rowp == 65) {
    for (int idx = t; idx < 1056; idx += 256) xq[obase + idx] = 0;
    return;
  }
  __shared__ __align__(16) unsigned short xs2[1056];
  int row = rowp - 1;
  for (int idx = t; idx < 1056; idx += 256) xs2[idx] = 0;
  __syncthreads();
#pragma unroll
  for (int k = 0; k < 4; ++k) {
    int idx = t + k * 256;  // 0..1023
    int il = idx >> 6, col = idx & 63;
    float v = x[(((size_t)b * 256 + c * 16 + il) * 64 + row) * 64 + col];
    xs2[(col + 1) * 16 + il] = f2bf(v);
  }
  __syncthreads();
  if (t < 132) {
    int G = blk * 132 + t;                 // global 16B-group index
    int flip = ((G >> 3) & 1) ^ (bc & 1);  // LDS-byte-bit7 of this group
    *(short8*)(xq + obase + (size_t)(t ^ flip) * 8) = *(const short8*)&xs2[t * 8];
  }
}

// ---------------------------------------------------------------------------
// Kernel 3: implicit-GEMM conv, ds_read-level software pipeline.
// Grid 256 (XCD-clustered); block 512 thr (8 waves), wave = out row.
// ---------------------------------------------------------------------------
__global__ __launch_bounds__(512, 2) void conv_mfma(
    const unsigned short* __restrict__ xq, const unsigned short* __restrict__ wq,
    float* __restrict__ out) {
  __shared__ __align__(16) unsigned short wsm[2][20480];  // [p20][ol128][e8]
  __shared__ __align__(16) unsigned short xsm[2][10560];  // [rl10][colp66][i16]

  int bid = blockIdx.x;
  int xcd = bid & 7;
  int kk = bid >> 3;            // 0..31
  int b = xcd * 2 + (kk >> 4);  // 2 batches per XCD
  int rem = kk & 15;
  int ot = rem >> 3;  // 128-o half
  int rt = rem & 7;   // 8-row tile
  int r0 = rt * 8;

  int t = threadIdx.x;
  int w = t >> 6, lane = t & 63;
  int g = (t >> 4) & 3, lm = t & 15;

  int baddr_[5], aaddr_[5];
#pragma unroll
  for (int s = 0; s < 5; ++s) {
    int p = 4 * s + g;
    int io = (p >= 10) ? 1 : 0;
    int j = p - 10 * io;
    int jd3, jm3;
    if (j == 9) { jd3 = 0; jm3 = 0; }  // dummy tap: weights zero
    else { jd3 = (j >= 3) + (j >= 6); jm3 = j - 3 * jd3; }
    int ba = ((w + jd3) * 66 + lm + jm3) * 32 + io * 16;
    ba ^= ((ba >> 7) & 1) << 4;      // matches xprep pre-swizzle
    baddr_[s] = ba;                  // + nf*512 at use (bit7 untouched)
    aaddr_[s] = p * 2048 + lm * 16;  // + mf*256 at use (bytes)
  }

  f32x4 acc[8][4];
#pragma unroll
  for (int mf = 0; mf < 8; ++mf)
#pragma unroll
    for (int nf = 0; nf < 4; ++nf) acc[mf][nf] = (f32x4){0.f, 0.f, 0.f, 0.f};

#define WGLL(cn, nb, r)                                                          \
  {                                                                              \
    const unsigned short* s_ = wq + ((size_t)(b * 32 + ot * 16 + (cn))) * 20480  \
                               + ((r) * 512 + w * 64 + lane) * 8;                \
    GLL16(s_, &wsm[nb][(r) * 4096 + w * 512]);                                   \
  }
#define XGLL(cn, nb, r)                                                          \
  {                                                                              \
    const unsigned short* s_ = xq + ((size_t)((b * 16 + (cn)) * 66 + r0)) * 1056 \
                               + ((r) * 512 + w * 64 + lane) * 8;                \
    GLL16(s_, &xsm[nb][(r) * 4096 + w * 512]);                                   \
  }

  short8 PA[8], PB[4], QA[8], QB[4];

#define DSRD(SA, SB_, cbuf, s)                                                  \
  {                                                                             \
    const char* wsb_ = (const char*)wsm[cbuf];                                  \
    const char* xsb_ = (const char*)xsm[cbuf];                                  \
    _Pragma("unroll")                                                           \
    for (int mf = 0; mf < 8; ++mf)                                              \
      SA[mf] = *(const short8*)(wsb_ + aaddr_[s] + mf * 256);                   \
    _Pragma("unroll")                                                           \
    for (int nf = 0; nf < 4; ++nf)                                              \
      SB_[nf] = *(const short8*)(xsb_ + baddr_[s] + nf * 512);                  \
  }

#define MFMA32(SA, SB_)                                                         \
  {                                                                             \
    __builtin_amdgcn_s_setprio(1);                                              \
    _Pragma("unroll")                                                           \
    for (int nf = 0; nf < 4; ++nf)                                              \
      _Pragma("unroll")                                                         \
      for (int mf = 0; mf < 8; ++mf)                                            \
        acc[mf][nf] = __builtin_amdgcn_mfma_f32_16x16x32_bf16(                  \
            SA[mf], SB_[nf], acc[mf][nf], 0, 0, 0);                             \
    __builtin_amdgcn_s_setprio(0);                                              \
  }

#define SBAR __builtin_amdgcn_sched_barrier(0)
#define LGKM0 asm volatile("s_waitcnt lgkmcnt(0)" ::: "memory")
#define VM0 asm volatile("s_waitcnt vmcnt(0)" ::: "memory")

  // prologue: stage c=0 into buffer 0, load R(0,s0) -> P
  WGLL(0, 0, 0); WGLL(0, 0, 1); WGLL(0, 0, 2); WGLL(0, 0, 3); WGLL(0, 0, 4);
  XGLL(0, 0, 0); XGLL(0, 0, 1);
  if (t < 296) XGLL(0, 0, 2);
  VM0;
  __builtin_amdgcn_s_barrier();
  SBAR;
  DSRD(PA, PB, 0, 0);

  for (int cc = 0; cc < 16; cc += 2) {
    // ---- first half: compute c=cc from buf0, stage cc+1 -> buf1 ----
    DSRD(QA, QB, 0, 1); WGLL(cc + 1, 1, 0); WGLL(cc + 1, 1, 1); SBAR;
    MFMA32(PA, PB);
    DSRD(PA, PB, 0, 2); WGLL(cc + 1, 1, 2); WGLL(cc + 1, 1, 3); SBAR;
    MFMA32(QA, QB);
    DSRD(QA, QB, 0, 3); WGLL(cc + 1, 1, 4); XGLL(cc + 1, 1, 0); SBAR;
    MFMA32(PA, PB);
    DSRD(PA, PB, 0, 4); XGLL(cc + 1, 1, 1);
    if (t < 296) XGLL(cc + 1, 1, 2);
    SBAR;
    MFMA32(QA, QB);
    LGKM0; SBAR;        // all buf0 reads consumed
    VM0;                // buf1 staging landed (issued >=1 phase ago)
    __builtin_amdgcn_s_barrier();
    SBAR;
    DSRD(QA, QB, 1, 0); SBAR;  // R(cc+1, s0); wait covered by s4 MFMA below
    MFMA32(PA, PB);
    // ---- second half: compute c=cc+1 from buf1, stage cc+2 -> buf0 ----
    if (cc < 14) {
      DSRD(PA, PB, 1, 1); WGLL(cc + 2, 0, 0); WGLL(cc + 2, 0, 1); SBAR;
      MFMA32(QA, QB);
      DSRD(QA, QB, 1, 2); WGLL(cc + 2, 0, 2); WGLL(cc + 2, 0, 3); SBAR;
      MFMA32(PA, PB);
      DSRD(PA, PB, 1, 3); WGLL(cc + 2, 0, 4); XGLL(cc + 2, 0, 0); SBAR;
      MFMA32(QA, QB);
      DSRD(QA, QB, 1, 4); XGLL(cc + 2, 0, 1);
      if (t < 296) XGLL(cc + 2, 0, 2);
      SBAR;
      MFMA32(PA, PB);
      LGKM0; SBAR;
      VM0;
      __builtin_amdgcn_s_barrier();
      SBAR;
      DSRD(PA, PB, 0, 0); SBAR;  // R(cc+2, s0)
      MFMA32(QA, QB);
    } else {
      DSRD(PA, PB, 1, 1); SBAR;
      MFMA32(QA, QB);
      DSRD(QA, QB, 1, 2); SBAR;
      MFMA32(PA, PB);
      DSRD(PA, PB, 1, 3); SBAR;
      MFMA32(QA, QB);
      DSRD(QA, QB, 1, 4); SBAR;
      MFMA32(PA, PB);
      MFMA32(QA, QB);
    }
  }

  // ---- epilogue: D col=lane&15 (px), row-in-frag=4*(lane>>4)+q (o) ----
  int row = r0 + w;
#pragma unroll
  for (int mf = 0; mf < 8; ++mf)
#pragma unroll
    for (int nf = 0; nf < 4; ++nf)
#pragma unroll
      for (int q = 0; q < 4; ++q) {
        int o = ot * 128 + mf * 16 + g * 4 + q;
        int col = nf * 16 + lm;
        out[(((size_t)b * 256 + o) * 64 + row) * 64 + col] = acc[mf][nf][q];
      }
#undef WGLL
#undef XGLL
#undef DSRD
#undef MFMA32
#undef SBAR
#undef LGKM0
#undef VM0
}

// ---------------------------------------------------------------------------
// Kernel 4: channel RMSNorm * gamma * 16 + SiLU, in place.
// ---------------------------------------------------------------------------
__global__ __launch_bounds__(256) void norm_kernel(
    float* __restrict__ y, const float* __restrict__ gamma) {
  int blk = blockIdx.x;
  int b = blk >> 6, h = blk & 63;
  int t = threadIdx.x;
  int p = t & 63, og = t >> 6;

  size_t base = (((size_t)b * 256) * 64 + h) * 64 + p;
  float yv[64];
  float s = 0.0f;
#pragma unroll
  for (int k = 0; k < 64; k++) {
    yv[k] = y[base + (size_t)(og * 64 + k) * 4096];
    s = fmaf(yv[k], yv[k], s);
  }

  __shared__ float red[4][64];
  __shared__ float invs[64];
  red[og][p] = s;
  __syncthreads();
  if (og == 0) {
    float tot = red[0][p] + red[1][p] + red[2][p] + red[3][p];
    float nrm = sqrtf(tot);
    invs[p] = 16.0f / fmaxf(nrm, 1e-12f);
  }
  __syncthreads();
  float iv = invs[p];
#pragma unroll
  for (int k = 0; k < 64; k++) {
    int o = og * 64 + k;
    float v = yv[k] * iv * gamma[o];
    float sg = 1.0f / (1.0f + expf(-v));
    y[base + (size_t)o * 4096] = v * sg;
  }
}

extern "C" void kernel_launch(void* const* d_in, const int* in_sizes, int n_in,
                              void* d_out, int out_size, void* d_ws, size_t ws_size,
                              hipStream_t stream) {
  const float* x = (const float*)d_in[0];
  const float* mod = (const float*)d_in[1];
  const float* kmod = (const float*)d_in[2];
  const float* weights = (const float*)d_in[3];
  const float* gamma = (const float*)d_in[4];
  float* out = (float*)d_out;

  // ws layout: wq 20,971,520 B | (gap) | xq 35,684,352 B  (~56.7 MB)
  unsigned short* wq = (unsigned short*)d_ws;
  unsigned short* xq = (unsigned short*)((char*)d_ws + 20987904);

  wprep<<<512, 256, 0, stream>>>(mod, kmod, weights, wq);
  xprep<<<16 * 16 * 66, 256, 0, stream>>>(x, xq);
  conv_mfma<<<256, 512, 0, stream>>>(xq, wq, out);
  norm_kernel<<<16 * 64, 256, 0, stream>>>(out, gamma);
}

// Round 9
// 285.720 us; speedup vs baseline: 1.5869x; 1.5869x over previous
//
#include <hip/hip_runtime.h>
#include <math.h>

// B=16, C_IN=256, C_OUT=256, H=W=64, K=3, NK=2
// weights: [2][256][256][3][3]; bank stride 589824 floats; per-o stride 2304.
//
// Pipeline:
//  1. wprep (fused scale+prep): combined+modulated+demod bf16 weights -> wq,
//     LINEAR-A LDS-image per (b,ot2,c16): [s5][mf8][g4][lm16][e8] (20480 ush),
//     where p = 4s+g = io*10 + j (j=9 zero dummy tap), o = ot*128+mf*16+lm.
//     A-read in conv = base + lane*16 + imm(s*8192+mf*1024): conflict-free.
//  2. xprep: x -> bf16 xq [b][c16][rowp 66][colp 66][io2][e8], halo zeros,
//     pre-swizzled 2-bit XOR (byte bit7->4, bit8->5) for conflict-light B reads.
//  3. conv_mfma: implicit GEMM mfma_f32_16x16x32_bf16. Block = 256 thr
//     (4 waves, 1 wave/SIMD, up to 512 VGPR) = 128 o x 8 rows x 64 px; grid 256.
//     Wave tile mf8 x nf8 (2 rows), acc 256 f32. ds_read-level software
//     pipeline (P/Q register sets, reads one phase ahead), GLL staging for c+1
//     spread over phases 0-3, one covered vmcnt(0)+barrier per c-step.
//  4. norm_kernel: channel RMSNorm * gamma * 16 + SiLU in place.

typedef __attribute__((ext_vector_type(8))) short short8;
typedef __attribute__((ext_vector_type(4))) float f32x4;

#define GLL16(src, dst)                                                       \
  __builtin_amdgcn_global_load_lds(                                           \
      (const __attribute__((address_space(1))) unsigned int*)(src),           \
      (__attribute__((address_space(3))) unsigned int*)(dst), 16, 0, 0)

static __device__ __forceinline__ unsigned short f2bf(float v) {
  union { float f; unsigned u; } u;
  u.f = v;
  unsigned r = u.u + 0x7FFF + ((u.u >> 16) & 1);  // RNE
  return (unsigned short)(r >> 16);
}

// ---------------------------------------------------------------------------
// Kernel 1: fused weight prep. Grid 512 = b(16) x oq(32 o-octets), 256 thr.
// ---------------------------------------------------------------------------
__global__ __launch_bounds__(256) void wprep(
    const float* __restrict__ mod, const float* __restrict__ kmod,
    const float* __restrict__ weights, unsigned short* __restrict__ wq) {
  int blk = blockIdx.x;  // b*32 + oq
  int b = blk >> 5, oq = blk & 31;
  int t = threadIdx.x;
  int o_l = t >> 5, its = t & 31;
  int o = oq * 8 + o_l;

  float k0 = kmod[b * 2 + 0], k1 = kmod[b * 2 + 1];
  float mx = fmaxf(k0, k1);
  float e0 = expf(k0 - mx), e1 = expf(k1 - mx);
  float ai = 1.0f / (e0 + e1);
  float a0 = e0 * ai, a1 = e1 * ai;

  float wv[9][8];  // [j][e]
  float s = 0.0f;
  const float* w0 = &weights[((size_t)o * 256 + its * 8) * 9];
  const float* w1 = w0 + 589824;
#pragma unroll
  for (int e = 0; e < 8; ++e) {
    float f = mod[b * 256 + its * 8 + e] + 1.0f;
#pragma unroll
    for (int j = 0; j < 9; ++j) {
      float v = (a0 * w0[e * 9 + j] + a1 * w1[e * 9 + j]) * f;
      wv[j][e] = v;
      s = fmaf(v, v, s);
    }
  }

  __shared__ float red[8][32];
  __shared__ float scl[8];
  red[o_l][its] = s;
  __syncthreads();
  if (t < 8) {
    float tot = 0.0f;
#pragma unroll
    for (int k = 0; k < 32; ++k) tot += red[t][k];
    scl[t] = rsqrtf(fmaxf(tot, 1e-8f));
  }
  __syncthreads();
  float sc = scl[o_l];

  int c = its >> 1, io = its & 1;
  int ot = o >> 7, mf = (o & 127) >> 4, lm = o & 15;
  size_t cbase = ((size_t)(b * 32 + ot * 16 + c)) * 20480;
#pragma unroll
  for (int j = 0; j < 9; ++j) {
    int p = io * 10 + j;
    int sp = p >> 2, g = p & 3;
    short8 pk;
#pragma unroll
    for (int e = 0; e < 8; ++e) pk[e] = (short)f2bf(wv[j][e] * sc);
    *(short8*)(wq + cbase + sp * 4096 + mf * 512 + g * 128 + lm * 8) = pk;
  }
  // dummy-tap zeros: p = 9 (s2,g1) and p = 19 (s4,g3); 8 o x 16 c x 2 io slots
  {
    int c2 = t >> 4, io2 = (t >> 3) & 1, olq = t & 7;
    int o2 = oq * 8 + olq;
    int ot2 = o2 >> 7, mf2 = (o2 & 127) >> 4, lm2 = o2 & 15;
    int p2 = io2 * 10 + 9;
    int sp2 = p2 >> 2, g2 = p2 & 3;
    short8 z = {0, 0, 0, 0, 0, 0, 0, 0};
    *(short8*)(wq + ((size_t)(b * 32 + ot2 * 16 + c2)) * 20480 + sp2 * 4096 +
               mf2 * 512 + g2 * 128 + lm2 * 8) = z;
  }
}

// ---------------------------------------------------------------------------
// Kernel 2: x prep -> bf16 xq, pre-swizzled (2-bit XOR).
// Logical slab byte L = rl*2112 + t*16; bits7,8(L) = bits3,4(4*(rowp%8)+t)
// (consistent across blocks since r0 % 8 == 0). Store granule t at t^fl.
// ---------------------------------------------------------------------------
__global__ __launch_bounds__(256) void xprep(
    const float* __restrict__ x, unsigned short* __restrict__ xq) {
  int blk = blockIdx.x;  // (b*16 + c)*66 + rowp
  int rowp = blk % 66;
  int bc = blk / 66;
  int b = bc >> 4, c = bc & 15;
  int t = threadIdx.x;
  size_t obase = (size_t)blk * 1056;

  if (rowp == 0 || rowp == 65) {
    for (int idx = t; idx < 1056; idx += 256) xq[obase + idx] = 0;
    return;
  }
  __shared__ __align__(16) unsigned short xs2[1056];
  int row = rowp - 1;
  for (int idx = t; idx < 1056; idx += 256) xs2[idx] = 0;
  __syncthreads();
#pragma unroll
  for (int k = 0; k < 4; ++k) {
    int idx = t + k * 256;  // 0..1023
    int il = idx >> 6, col = idx & 63;
    float v = x[(((size_t)b * 256 + c * 16 + il) * 64 + row) * 64 + col];
    xs2[(col + 1) * 16 + il] = f2bf(v);
  }
  __syncthreads();
  if (t < 132) {
    int S = 4 * (rowp & 7) + t;
    int fl = ((S >> 3) & 1) | (((S >> 4) & 1) << 1);
    *(short8*)(xq + obase + (size_t)(t ^ fl) * 8) = *(const short8*)&xs2[t * 8];
  }
}

// ---------------------------------------------------------------------------
// Kernel 3: implicit-GEMM conv. 4 waves, 1 wave/SIMD, mf8 x nf8, acc 256.
// Grid 256 (XCD-clustered).
// ---------------------------------------------------------------------------
__global__ __launch_bounds__(256, 1) void conv_mfma(
    const unsigned short* __restrict__ xq, const unsigned short* __restrict__ wq,
    float* __restrict__ out) {
  __shared__ __align__(16) unsigned short wsm[2][20480];  // [s5][mf8][lane64][e8]
  __shared__ __align__(16) unsigned short xsm[2][10560];  // [rl10][colp66][io2][e8]

  int bid = blockIdx.x;
  int xcd = bid & 7;
  int kk = bid >> 3;            // 0..31
  int b = xcd * 2 + (kk >> 4);  // 2 batches per XCD
  int rem = kk & 15;
  int ot = rem >> 3;  // 128-o half
  int rt = rem & 7;   // 8-row tile
  int r0 = rt * 8;

  int t = threadIdx.x;
  int w = t >> 6, lane = t & 63;
  int g = (t >> 4) & 3, lm = t & 15;
  int aoff = lane * 16;  // A-read per-lane byte offset (single VGPR)

  // B logical addresses per phase s, for the wave's two rows (rr = 0,1),
  // swizzled; +nc*512 (bit9+) added at use.
  int b0_[5], b1_[5];
#pragma unroll
  for (int s = 0; s < 5; ++s) {
    int p = 4 * s + g;
    int io = (p >= 10) ? 1 : 0;
    int j = p - 10 * io;
    int jd3, jm3;
    if (j == 9) { jd3 = 0; jm3 = 0; }  // dummy tap: weights zero
    else { jd3 = (j >= 3) + (j >= 6); jm3 = j - 3 * jd3; }
    int la0 = ((2 * w + jd3) * 66 + lm + jm3) * 32 + io * 16;
    la0 ^= (((la0 >> 7) & 1) << 4) ^ (((la0 >> 8) & 1) << 5);
    b0_[s] = la0;
    int la1 = ((2 * w + 1 + jd3) * 66 + lm + jm3) * 32 + io * 16;
    la1 ^= (((la1 >> 7) & 1) << 4) ^ (((la1 >> 8) & 1) << 5);
    b1_[s] = la1;
  }

  f32x4 acc[8][8];
#pragma unroll
  for (int mf = 0; mf < 8; ++mf)
#pragma unroll
    for (int nf = 0; nf < 8; ++nf) acc[mf][nf] = (f32x4){0.f, 0.f, 0.f, 0.f};

#define WGLL(cn, nb, r)                                                         \
  {                                                                             \
    const unsigned short* s_ =                                                  \
        wq + ((size_t)(b * 32 + ot * 16 + (cn))) * 20480 + ((r) * 256 + t) * 8; \
    GLL16(s_, &wsm[nb][((r) * 256 + t) * 8]);                                   \
  }
#define XGLL(cn, nb, r)                                                          \
  {                                                                              \
    const unsigned short* s_ =                                                   \
        xq + ((size_t)((b * 16 + (cn)) * 66 + r0)) * 1056 + ((r) * 256 + t) * 8; \
    GLL16(s_, &xsm[nb][((r) * 256 + t) * 8]);                                    \
  }
#define XGLLP(cn, nb)                                                            \
  {                                                                              \
    const unsigned short* s_ =                                                   \
        xq + ((size_t)((b * 16 + (cn)) * 66 + r0)) * 1056 + (1280 + t) * 8;      \
    GLL16(s_, &xsm[nb][(1280 + t) * 8]);                                         \
  }

  short8 PA[8], PB[8], QA[8], QB[8];

#define DSRD(SA, SB, cbuf, s)                                                   \
  {                                                                             \
    const char* wsb_ = (const char*)wsm[cbuf] + aoff;                           \
    const char* xsb_ = (const char*)xsm[cbuf];                                  \
    _Pragma("unroll")                                                           \
    for (int mf = 0; mf < 8; ++mf)                                              \
      SA[mf] = *(const short8*)(wsb_ + (s) * 8192 + mf * 1024);                 \
    _Pragma("unroll")                                                           \
    for (int nc = 0; nc < 4; ++nc) {                                            \
      SB[nc] = *(const short8*)(xsb_ + b0_[s] + nc * 512);                      \
      SB[4 + nc] = *(const short8*)(xsb_ + b1_[s] + nc * 512);                  \
    }                                                                           \
  }

#define MFMA64(SA, SB)                                                          \
  {                                                                             \
    __builtin_amdgcn_s_setprio(1);                                              \
    _Pragma("unroll")                                                           \
    for (int nf = 0; nf < 8; ++nf)                                              \
      _Pragma("unroll")                                                         \
      for (int mf = 0; mf < 8; ++mf)                                            \
        acc[mf][nf] = __builtin_amdgcn_mfma_f32_16x16x32_bf16(                  \
            SA[mf], SB[nf], acc[mf][nf], 0, 0, 0);                              \
    __builtin_amdgcn_s_setprio(0);                                              \
  }

#define SBAR __builtin_amdgcn_sched_barrier(0)
#define LGKM0 asm volatile("s_waitcnt lgkmcnt(0)" ::: "memory")
#define VM0 asm volatile("s_waitcnt vmcnt(0)" ::: "memory")

  // RA0/RB0 hold phase s0 data at body entry; RA1/RB1 are the other set.
#define CBODY(RA0, RB0, RA1, RB1, cb, nb, cn)                                   \
  {                                                                             \
    DSRD(RA1, RB1, cb, 1);                                                      \
    WGLL(cn + 1, nb, 0); WGLL(cn + 1, nb, 1);                                   \
    WGLL(cn + 1, nb, 2); WGLL(cn + 1, nb, 3);                                   \
    SBAR;                                                                       \
    MFMA64(RA0, RB0);                                                           \
    DSRD(RA0, RB0, cb, 2);                                                      \
    WGLL(cn + 1, nb, 4); WGLL(cn + 1, nb, 5);                                   \
    WGLL(cn + 1, nb, 6); WGLL(cn + 1, nb, 7);                                   \
    SBAR;                                                                       \
    MFMA64(RA1, RB1);                                                           \
    DSRD(RA1, RB1, cb, 3);                                                      \
    WGLL(cn + 1, nb, 8); WGLL(cn + 1, nb, 9);                                   \
    XGLL(cn + 1, nb, 0); XGLL(cn + 1, nb, 1);                                   \
    SBAR;                                                                       \
    MFMA64(RA0, RB0);                                                           \
    DSRD(RA0, RB0, cb, 4);                                                      \
    XGLL(cn + 1, nb, 2); XGLL(cn + 1, nb, 3); XGLL(cn + 1, nb, 4);              \
    if (t < 40) XGLLP(cn + 1, nb);                                              \
    SBAR;                                                                       \
    MFMA64(RA1, RB1);                                                           \
    LGKM0; SBAR;                                                                \
    VM0;                                                                        \
    __builtin_amdgcn_s_barrier();                                               \
    SBAR;                                                                       \
    DSRD(RA1, RB1, nb, 0); SBAR;                                                \
    MFMA64(RA0, RB0);                                                           \
  }

#define CTAIL(RA0, RB0, RA1, RB1, cb)                                           \
  {                                                                             \
    DSRD(RA1, RB1, cb, 1); SBAR; MFMA64(RA0, RB0);                              \
    DSRD(RA0, RB0, cb, 2); SBAR; MFMA64(RA1, RB1);                              \
    DSRD(RA1, RB1, cb, 3); SBAR; MFMA64(RA0, RB0);                              \
    DSRD(RA0, RB0, cb, 4); SBAR; MFMA64(RA1, RB1);                              \
    MFMA64(RA0, RB0);                                                           \
  }

  // prologue: stage c=0 into buffer 0; preload P = R(c0, s0)
  WGLL(0, 0, 0); WGLL(0, 0, 1); WGLL(0, 0, 2); WGLL(0, 0, 3); WGLL(0, 0, 4);
  WGLL(0, 0, 5); WGLL(0, 0, 6); WGLL(0, 0, 7); WGLL(0, 0, 8); WGLL(0, 0, 9);
  XGLL(0, 0, 0); XGLL(0, 0, 1); XGLL(0, 0, 2); XGLL(0, 0, 3); XGLL(0, 0, 4);
  if (t < 40) XGLLP(0, 0);
  VM0;
  __builtin_amdgcn_s_barrier();
  SBAR;
  DSRD(PA, PB, 0, 0);
  SBAR;

  for (int cc = 0; cc < 16; cc += 2) {
    CBODY(PA, PB, QA, QB, 0, 1, cc);
    if (cc < 14) {
      CBODY(QA, QB, PA, PB, 1, 0, cc + 1);
    } else {
      CTAIL(QA, QB, PA, PB, 1);
    }
  }

  // ---- epilogue: D col=lane&15 (px within 16), row-in-frag=g*4+q (o) ----
#pragma unroll
  for (int mf = 0; mf < 8; ++mf)
#pragma unroll
    for (int nf = 0; nf < 8; ++nf) {
      int row = r0 + 2 * w + (nf >> 2);
      int col = (nf & 3) * 16 + lm;
#pragma unroll
      for (int q = 0; q < 4; ++q) {
        int o = ot * 128 + mf * 16 + g * 4 + q;
        out[(((size_t)b * 256 + o) * 64 + row) * 64 + col] = acc[mf][nf][q];
      }
    }
#undef WGLL
#undef XGLL
#undef XGLLP
#undef DSRD
#undef MFMA64
#undef SBAR
#undef LGKM0
#undef VM0
#undef CBODY
#undef CTAIL
}

// ---------------------------------------------------------------------------
// Kernel 4: channel RMSNorm * gamma * 16 + SiLU, in place.
// ---------------------------------------------------------------------------
__global__ __launch_bounds__(256) void norm_kernel(
    float* __restrict__ y, const float* __restrict__ gamma) {
  int blk = blockIdx.x;
  int b = blk >> 6, h = blk & 63;
  int t = threadIdx.x;
  int p = t & 63, og = t >> 6;

  size_t base = (((size_t)b * 256) * 64 + h) * 64 + p;
  float yv[64];
  float s = 0.0f;
#pragma unroll
  for (int k = 0; k < 64; k++) {
    yv[k] = y[base + (size_t)(og * 64 + k) * 4096];
    s = fmaf(yv[k], yv[k], s);
  }

  __shared__ float red[4][64];
  __shared__ float invs[64];
  red[og][p] = s;
  __syncthreads();
  if (og == 0) {
    float tot = red[0][p] + red[1][p] + red[2][p] + red[3][p];
    float nrm = sqrtf(tot);
    invs[p] = 16.0f / fmaxf(nrm, 1e-12f);
  }
  __syncthreads();
  float iv = invs[p];
#pragma unroll
  for (int k = 0; k < 64; k++) {
    int o = og * 64 + k;
    float v = yv[k] * iv * gamma[o];
    float sg = 1.0f / (1.0f + expf(-v));
    y[base + (size_t)o * 4096] = v * sg;
  }
}

extern "C" void kernel_launch(void* const* d_in, const int* in_sizes, int n_in,
                              void* d_out, int out_size, void* d_ws, size_t ws_size,
                              hipStream_t stream) {
  const float* x = (const float*)d_in[0];
  const float* mod = (const float*)d_in[1];
  const float* kmod = (const float*)d_in[2];
  const float* weights = (const float*)d_in[3];
  const float* gamma = (const float*)d_in[4];
  float* out = (float*)d_out;

  // ws layout: wq 20,971,520 B | (gap) | xq 35,684,352 B  (~56.7 MB)
  unsigned short* wq = (unsigned short*)d_ws;
  unsigned short* xq = (unsigned short*)((char*)d_ws + 20987904);

  wprep<<<512, 256, 0, stream>>>(mod, kmod, weights, wq);
  xprep<<<16 * 16 * 66, 256, 0, stream>>>(x, xq);
  conv_mfma<<<256, 256, 0, stream>>>(xq, wq, out);
  norm_kernel<<<16 * 64, 256, 0, stream>>>(out, gamma);
}

// Round 10
// 136.895 us; speedup vs baseline: 3.3120x; 2.0871x over previous
//
#include <hip/hip_runtime.h>
#include <math.h>

// B=16, C_IN=256, C_OUT=256, H=W=64, K=3, NK=2
// weights: [2][256][256][3][3]; bank stride 589824 floats; per-o stride 2304.
//
// Pipeline:
//  1. wprep (fused scale+prep): combined+modulated+demod bf16 weights -> wq,
//     LINEAR-A LDS-image per (b,ot2,c16): [s5][mf8][g4][lm16][e8] (20480 ush),
//     where p = 4s+g = io*10 + j (j=9 zero dummy tap), o = ot*128+mf*16+lm.
//     A-read in conv = base + lane*16 + imm(s*8192+mf*1024): conflict-free.
//  2. xprep: x -> bf16 xq [b][c16][rowp 66][colp 66][io2][e8], halo zeros,
//     pre-swizzled 2-bit XOR (byte bit7->4, bit8->5) for conflict-light B reads.
//  3. conv_mfma: implicit GEMM mfma_f32_16x16x32_bf16. Block = 256 thr
//     (4 waves, 1 wave/SIMD) = 128 o x 8 rows x 64 px; grid 256. Wave tile
//     mf8 x nf8 (acc 256 f32 -> AGPR side), fragments read INLINE per phase
//     (no register double-buffer -> no spill), compiler pipelines ds_reads.
//     GLL staging for c+1 spread over phases 0-3; LGKM0+VM0+barrier per c.
//  4. norm_kernel: channel RMSNorm * gamma * 16 + SiLU in place.

typedef __attribute__((ext_vector_type(8))) short short8;
typedef __attribute__((ext_vector_type(4))) float f32x4;

#define GLL16(src, dst)                                                       \
  __builtin_amdgcn_global_load_lds(                                           \
      (const __attribute__((address_space(1))) unsigned int*)(src),           \
      (__attribute__((address_space(3))) unsigned int*)(dst), 16, 0, 0)

static __device__ __forceinline__ unsigned short f2bf(float v) {
  union { float f; unsigned u; } u;
  u.f = v;
  unsigned r = u.u + 0x7FFF + ((u.u >> 16) & 1);  // RNE
  return (unsigned short)(r >> 16);
}

// ---------------------------------------------------------------------------
// Kernel 1: fused weight prep. Grid 512 = b(16) x oq(32 o-octets), 256 thr.
// ---------------------------------------------------------------------------
__global__ __launch_bounds__(256) void wprep(
    const float* __restrict__ mod, const float* __restrict__ kmod,
    const float* __restrict__ weights, unsigned short* __restrict__ wq) {
  int blk = blockIdx.x;  // b*32 + oq
  int b = blk >> 5, oq = blk & 31;
  int t = threadIdx.x;
  int o_l = t >> 5, its = t & 31;
  int o = oq * 8 + o_l;

  float k0 = kmod[b * 2 + 0], k1 = kmod[b * 2 + 1];
  float mx = fmaxf(k0, k1);
  float e0 = expf(k0 - mx), e1 = expf(k1 - mx);
  float ai = 1.0f / (e0 + e1);
  float a0 = e0 * ai, a1 = e1 * ai;

  float wv[9][8];  // [j][e]
  float s = 0.0f;
  const float* w0 = &weights[((size_t)o * 256 + its * 8) * 9];
  const float* w1 = w0 + 589824;
#pragma unroll
  for (int e = 0; e < 8; ++e) {
    float f = mod[b * 256 + its * 8 + e] + 1.0f;
#pragma unroll
    for (int j = 0; j < 9; ++j) {
      float v = (a0 * w0[e * 9 + j] + a1 * w1[e * 9 + j]) * f;
      wv[j][e] = v;
      s = fmaf(v, v, s);
    }
  }

  __shared__ float red[8][32];
  __shared__ float scl[8];
  red[o_l][its] = s;
  __syncthreads();
  if (t < 8) {
    float tot = 0.0f;
#pragma unroll
    for (int k = 0; k < 32; ++k) tot += red[t][k];
    scl[t] = rsqrtf(fmaxf(tot, 1e-8f));
  }
  __syncthreads();
  float sc = scl[o_l];

  int c = its >> 1, io = its & 1;
  int ot = o >> 7, mf = (o & 127) >> 4, lm = o & 15;
  size_t cbase = ((size_t)(b * 32 + ot * 16 + c)) * 20480;
#pragma unroll
  for (int j = 0; j < 9; ++j) {
    int p = io * 10 + j;
    int sp = p >> 2, g = p & 3;
    short8 pk;
#pragma unroll
    for (int e = 0; e < 8; ++e) pk[e] = (short)f2bf(wv[j][e] * sc);
    *(short8*)(wq + cbase + sp * 4096 + mf * 512 + g * 128 + lm * 8) = pk;
  }
  // dummy-tap zeros: p = 9 (s2,g1) and p = 19 (s4,g3); 8 o x 16 c x 2 io slots
  {
    int c2 = t >> 4, io2 = (t >> 3) & 1, olq = t & 7;
    int o2 = oq * 8 + olq;
    int ot2 = o2 >> 7, mf2 = (o2 & 127) >> 4, lm2 = o2 & 15;
    int p2 = io2 * 10 + 9;
    int sp2 = p2 >> 2, g2 = p2 & 3;
    short8 z = {0, 0, 0, 0, 0, 0, 0, 0};
    *(short8*)(wq + ((size_t)(b * 32 + ot2 * 16 + c2)) * 20480 + sp2 * 4096 +
               mf2 * 512 + g2 * 128 + lm2 * 8) = z;
  }
}

// ---------------------------------------------------------------------------
// Kernel 2: x prep -> bf16 xq, pre-swizzled (2-bit XOR).
// ---------------------------------------------------------------------------
__global__ __launch_bounds__(256) void xprep(
    const float* __restrict__ x, unsigned short* __restrict__ xq) {
  int blk = blockIdx.x;  // (b*16 + c)*66 + rowp
  int rowp = blk % 66;
  int bc = blk / 66;
  int b = bc >> 4, c = bc & 15;
  int t = threadIdx.x;
  size_t obase = (size_t)blk * 1056;

  if (rowp == 0 || rowp == 65) {
    for (int idx = t; idx < 1056; idx += 256) xq[obase + idx] = 0;
    return;
  }
  __shared__ __align__(16) unsigned short xs2[1056];
  int row = rowp - 1;
  for (int idx = t; idx < 1056; idx += 256) xs2[idx] = 0;
  __syncthreads();
#pragma unroll
  for (int k = 0; k < 4; ++k) {
    int idx = t + k * 256;  // 0..1023
    int il = idx >> 6, col = idx & 63;
    float v = x[(((size_t)b * 256 + c * 16 + il) * 64 + row) * 64 + col];
    xs2[(col + 1) * 16 + il] = f2bf(v);
  }
  __syncthreads();
  if (t < 132) {
    int S = 4 * (rowp & 7) + t;
    int fl = ((S >> 3) & 1) | (((S >> 4) & 1) << 1);
    *(short8*)(xq + obase + (size_t)(t ^ fl) * 8) = *(const short8*)&xs2[t * 8];
  }
}

// ---------------------------------------------------------------------------
// Kernel 3: implicit-GEMM conv. 4 waves, 1 wave/SIMD, mf8 x nf8, acc 256.
// Fragments read inline (no reg double-buffer). Grid 256 (XCD-clustered).
// ---------------------------------------------------------------------------
__global__ __launch_bounds__(256, 1) void conv_mfma(
    const unsigned short* __restrict__ xq, const unsigned short* __restrict__ wq,
    float* __restrict__ out) {
  __shared__ __align__(16) unsigned short wsm[2][20480];  // [s5][mf8][lane64][e8]
  __shared__ __align__(16) unsigned short xsm[2][10560];  // [rl10][colp66][io2][e8]

  int bid = blockIdx.x;
  int xcd = bid & 7;
  int kk = bid >> 3;            // 0..31
  int b = xcd * 2 + (kk >> 4);  // 2 batches per XCD
  int rem = kk & 15;
  int ot = rem >> 3;  // 128-o half
  int rt = rem & 7;   // 8-row tile
  int r0 = rt * 8;

  int t = threadIdx.x;
  int w = t >> 6, lane = t & 63;
  int g = (t >> 4) & 3, lm = t & 15;
  int aoff = lane * 16;  // A-read per-lane byte offset

  // B addresses per phase s for the wave's two rows, swizzled; +nc*512 at use.
  int b0_[5], b1_[5];
#pragma unroll
  for (int s = 0; s < 5; ++s) {
    int p = 4 * s + g;
    int io = (p >= 10) ? 1 : 0;
    int j = p - 10 * io;
    int jd3, jm3;
    if (j == 9) { jd3 = 0; jm3 = 0; }  // dummy tap: weights zero
    else { jd3 = (j >= 3) + (j >= 6); jm3 = j - 3 * jd3; }
    int la0 = ((2 * w + jd3) * 66 + lm + jm3) * 32 + io * 16;
    la0 ^= (((la0 >> 7) & 1) << 4) ^ (((la0 >> 8) & 1) << 5);
    b0_[s] = la0;
    int la1 = ((2 * w + 1 + jd3) * 66 + lm + jm3) * 32 + io * 16;
    la1 ^= (((la1 >> 7) & 1) << 4) ^ (((la1 >> 8) & 1) << 5);
    b1_[s] = la1;
  }

  f32x4 acc[8][8];
#pragma unroll
  for (int mf = 0; mf < 8; ++mf)
#pragma unroll
    for (int nf = 0; nf < 8; ++nf) acc[mf][nf] = (f32x4){0.f, 0.f, 0.f, 0.f};

#define WGLL(cn, nb, r)                                                         \
  {                                                                             \
    const unsigned short* s_ =                                                  \
        wq + ((size_t)(b * 32 + ot * 16 + (cn))) * 20480 + ((r) * 256 + t) * 8; \
    GLL16(s_, &wsm[nb][((r) * 256 + t) * 8]);                                   \
  }
#define XGLL(cn, nb, r)                                                          \
  {                                                                              \
    const unsigned short* s_ =                                                   \
        xq + ((size_t)((b * 16 + (cn)) * 66 + r0)) * 1056 + ((r) * 256 + t) * 8; \
    GLL16(s_, &xsm[nb][((r) * 256 + t) * 8]);                                    \
  }
#define XGLLP(cn, nb)                                                            \
  {                                                                              \
    const unsigned short* s_ =                                                   \
        xq + ((size_t)((b * 16 + (cn)) * 66 + r0)) * 1056 + (1280 + t) * 8;      \
    GLL16(s_, &xsm[nb][(1280 + t) * 8]);                                         \
  }

#define LGKM0 asm volatile("s_waitcnt lgkmcnt(0)" ::: "memory")
#define VM0 asm volatile("s_waitcnt vmcnt(0)" ::: "memory")

  // prologue: stage c=0 into buffer 0
  WGLL(0, 0, 0); WGLL(0, 0, 1); WGLL(0, 0, 2); WGLL(0, 0, 3); WGLL(0, 0, 4);
  WGLL(0, 0, 5); WGLL(0, 0, 6); WGLL(0, 0, 7); WGLL(0, 0, 8); WGLL(0, 0, 9);
  XGLL(0, 0, 0); XGLL(0, 0, 1); XGLL(0, 0, 2); XGLL(0, 0, 3); XGLL(0, 0, 4);
  if (t < 40) XGLLP(0, 0);
  VM0;
  __builtin_amdgcn_s_barrier();

  for (int c = 0; c < 16; ++c) {
    int cur = c & 1;
    const char* wsb = (const char*)wsm[cur] + aoff;
    const char* xsb = (const char*)xsm[cur];
#pragma unroll
    for (int s = 0; s < 5; ++s) {
      // staging issue for c+1, spread over phases 0-3
      if (c < 15) {
        int nb = cur ^ 1;
        if (s == 0) { WGLL(c + 1, nb, 0); WGLL(c + 1, nb, 1); WGLL(c + 1, nb, 2); }
        if (s == 1) { WGLL(c + 1, nb, 3); WGLL(c + 1, nb, 4); WGLL(c + 1, nb, 5); }
        if (s == 2) { WGLL(c + 1, nb, 6); WGLL(c + 1, nb, 7); WGLL(c + 1, nb, 8); }
        if (s == 3) {
          WGLL(c + 1, nb, 9);
          XGLL(c + 1, nb, 0); XGLL(c + 1, nb, 1); XGLL(c + 1, nb, 2);
          XGLL(c + 1, nb, 3); XGLL(c + 1, nb, 4);
          if (t < 40) XGLLP(c + 1, nb);
        }
      }
      short8 A[8], Bv[8];
#pragma unroll
      for (int mf = 0; mf < 8; ++mf)
        A[mf] = *(const short8*)(wsb + s * 8192 + mf * 1024);
#pragma unroll
      for (int nc = 0; nc < 4; ++nc) {
        Bv[nc] = *(const short8*)(xsb + b0_[s] + nc * 512);
        Bv[4 + nc] = *(const short8*)(xsb + b1_[s] + nc * 512);
      }
      __builtin_amdgcn_s_setprio(1);
#pragma unroll
      for (int nf = 0; nf < 8; ++nf)
#pragma unroll
        for (int mf = 0; mf < 8; ++mf)
          acc[mf][nf] = __builtin_amdgcn_mfma_f32_16x16x32_bf16(
              A[mf], Bv[nf], acc[mf][nf], 0, 0, 0);
      __builtin_amdgcn_s_setprio(0);
    }
    LGKM0;  // my reads of buf cur complete -> safe for others to overwrite later
    VM0;    // staging for c+1 landed (issued >=1 phase ago)
    __builtin_amdgcn_s_barrier();
  }

  // ---- epilogue: D col=lane&15 (px within 16), row-in-frag=g*4+q (o) ----
#pragma unroll
  for (int mf = 0; mf < 8; ++mf)
#pragma unroll
    for (int nf = 0; nf < 8; ++nf) {
      int row = r0 + 2 * w + (nf >> 2);
      int col = (nf & 3) * 16 + lm;
#pragma unroll
      for (int q = 0; q < 4; ++q) {
        int o = ot * 128 + mf * 16 + g * 4 + q;
        out[(((size_t)b * 256 + o) * 64 + row) * 64 + col] = acc[mf][nf][q];
      }
    }
#undef WGLL
#undef XGLL
#undef XGLLP
#undef LGKM0
#undef VM0
}

// ---------------------------------------------------------------------------
// Kernel 4: channel RMSNorm * gamma * 16 + SiLU, in place.
// ---------------------------------------------------------------------------
__global__ __launch_bounds__(256) void norm_kernel(
    float* __restrict__ y, const float* __restrict__ gamma) {
  int blk = blockIdx.x;
  int b = blk >> 6, h = blk & 63;
  int t = threadIdx.x;
  int p = t & 63, og = t >> 6;

  size_t base = (((size_t)b * 256) * 64 + h) * 64 + p;
  float yv[64];
  float s = 0.0f;
#pragma unroll
  for (int k = 0; k < 64; k++) {
    yv[k] = y[base + (size_t)(og * 64 + k) * 4096];
    s = fmaf(yv[k], yv[k], s);
  }

  __shared__ float red[4][64];
  __shared__ float invs[64];
  red[og][p] = s;
  __syncthreads();
  if (og == 0) {
    float tot = red[0][p] + red[1][p] + red[2][p] + red[3][p];
    float nrm = sqrtf(tot);
    invs[p] = 16.0f / fmaxf(nrm, 1e-12f);
  }
  __syncthreads();
  float iv = invs[p];
#pragma unroll
  for (int k = 0; k < 64; k++) {
    int o = og * 64 + k;
    float v = yv[k] * iv * gamma[o];
    float sg = 1.0f / (1.0f + expf(-v));
    y[base + (size_t)o * 4096] = v * sg;
  }
}

extern "C" void kernel_launch(void* const* d_in, const int* in_sizes, int n_in,
                              void* d_out, int out_size, void* d_ws, size_t ws_size,
                              hipStream_t stream) {
  const float* x = (const float*)d_in[0];
  const float* mod = (const float*)d_in[1];
  const float* kmod = (const float*)d_in[2];
  const float* weights = (const float*)d_in[3];
  const float* gamma = (const float*)d_in[4];
  float* out = (float*)d_out;

  // ws layout: wq 20,971,520 B | (gap) | xq 35,684,352 B  (~56.7 MB)
  unsigned short* wq = (unsigned short*)d_ws;
  unsigned short* xq = (unsigned short*)((char*)d_ws + 20987904);

  wprep<<<512, 256, 0, stream>>>(mod, kmod, weights, wq);
  xprep<<<16 * 16 * 66, 256, 0, stream>>>(x, xq);
  conv_mfma<<<256, 256, 0, stream>>>(xq, wq, out);
  norm_kernel<<<16 * 64, 256, 0, stream>>>(out, gamma);
}